// Round 1
// baseline (258.893 us; speedup 1.0000x reference)
//
#include <hip/hip_runtime.h>

typedef short short8 __attribute__((ext_vector_type(8)));
typedef float f32x4 __attribute__((ext_vector_type(4)));

#define LAYER_ELEMS (64 * 4096) // 262144 elements of W per layer

// fp32 -> bf16 round-to-nearest-even (3 VALU ops)
__device__ __forceinline__ unsigned short f2bf(float f) {
    unsigned int u = __float_as_uint(f);
    u += 0x7fffu + ((u >> 16) & 1u);
    return (unsigned short)(u >> 16);
}
__device__ __forceinline__ float bf2f(unsigned short h) {
    return __uint_as_float(((unsigned int)h) << 16);
}

// Repack W (fp32 row-major [o][c], c = i*64+j) into bf16 A-fragment order:
// Wf[l][kstep][otile][lane][t] = bf16( W_l[otile*16 + (lane&15)][kstep*32 + (lane>>4)*8 + t] )
// so the main kernel's A-frag load is one contiguous 16B ds_read_b128 per lane.
__global__ __launch_bounds__(256) void prepack_kernel(const float* __restrict__ W1,
                                                      const float* __restrict__ W2,
                                                      unsigned short* __restrict__ Wf) {
    int tid = blockIdx.x * 256 + threadIdx.x; // 0 .. 524287
    int l = tid >> 18;
    int r = tid & (LAYER_ELEMS - 1);
    int t = r & 7;
    int lane = (r >> 3) & 63;
    int ot = (r >> 9) & 3;
    int ks = r >> 11;
    int o = ot * 16 + (lane & 15);
    int c = ks * 32 + ((lane >> 4) << 3) + t;
    const float* W = l ? W2 : W1;
    Wf[tid] = f2bf(W[o * 4096 + c]);
}

// One block per batch element b. 4 waves: wave w owns d-tile w (16 cols) x all 64 o.
// Per K-step (K=32): i = kstep>>1 constant, j spans j0..j0+31 contiguous ->
// B-frag built from one ds_read_b128 of hT[d][j0 + quad*8 .. +8] times x[i][d].
__global__ __launch_bounds__(256) void cin_kernel(const float* __restrict__ x,
                                                  const unsigned short* __restrict__ Wf,
                                                  const float* __restrict__ b1,
                                                  const float* __restrict__ b2,
                                                  const float* __restrict__ Wfc,
                                                  const float* __restrict__ bfc,
                                                  float* __restrict__ out) {
    // stride 72 (bf16): rows 144 B = 9*16 -> 16B-aligned b128 reads, 2-way max bank aliasing (free)
    __shared__ __align__(16) unsigned short sXT[64 * 72]; // x^T  bf16 [d][i]
    __shared__ __align__(16) unsigned short sHT[64 * 72]; // h1^T bf16 [d][j]
    __shared__ __align__(16) unsigned short sWst[8 * 2048]; // 8 ksteps of A-frags (32 KB)
    __shared__ float sBiasA[64], sBiasB[64], sWfcS[128], sRed[4];

    const int tid = threadIdx.x;
    const int w = tid >> 6;    // wave id = d-tile
    const int lane = tid & 63;
    const int q = lane >> 4;   // quad
    const int n15 = lane & 15;
    const int d = w * 16 + n15; // this lane's d column
    const int bb = blockIdx.x;

    // ---- stage x (coalesced float4 global reads, transposed bf16 LDS writes) ----
    const float4* xb4 = (const float4*)(x + bb * 4096);
#pragma unroll
    for (int rr = 0; rr < 4; ++rr) {
        int e4 = rr * 256 + tid;
        float4 v = xb4[e4];
        int e = e4 << 2;
        int ii = e >> 6;
        int dd = e & 63;
        sXT[(dd + 0) * 72 + ii] = f2bf(v.x);
        sXT[(dd + 1) * 72 + ii] = f2bf(v.y);
        sXT[(dd + 2) * 72 + ii] = f2bf(v.z);
        sXT[(dd + 3) * 72 + ii] = f2bf(v.w);
    }
    if (tid < 64) {
        sBiasA[tid] = b1[tid];
        sBiasB[tid] = b2[tid];
    } else if (tid < 192) {
        sWfcS[tid - 64] = Wfc[tid - 64];
    }
    __syncthreads();

    float contrib = 0.0f; // this thread's partial of pooled @ Wfc^T

    for (int l = 0; l < 2; ++l) {
        const unsigned short* hsrc = l ? sHT : sXT; // j-factor source (h = x for layer 1)
        const unsigned short* WfL = Wf + l * LAYER_ELEMS;
        f32x4 acc0 = {0.f, 0.f, 0.f, 0.f};
        f32x4 acc1 = acc0, acc2 = acc0, acc3 = acc0;

        for (int chunk = 0; chunk < 16; ++chunk) {
            __syncthreads(); // protect sWst from readers of previous chunk
            {
                const uint4* src = (const uint4*)(WfL + chunk * 16384);
                uint4* dst = (uint4*)sWst;
#pragma unroll
                for (int e = 0; e < 8; ++e)
                    dst[e * 256 + tid] = src[e * 256 + tid];
            }
            __syncthreads();

            for (int ks8 = 0; ks8 < 8; ++ks8) {
                const int kstep = chunk * 8 + ks8;
                const int irow = kstep >> 1;       // i = c0 >> 6
                const int j0 = (kstep & 1) << 5;   // j0 = c0 & 63
                const float xv = bf2f(sXT[d * 72 + irow]);
                const short8 h8 = *(const short8*)&hsrc[d * 72 + j0 + q * 8];
                short8 bfrag;
#pragma unroll
                for (int t = 0; t < 8; ++t)
                    bfrag[t] = (short)f2bf(xv * bf2f((unsigned short)h8[t]));
                const short8* Wk = ((const short8*)sWst) + ks8 * 256 + lane;
                acc0 = __builtin_amdgcn_mfma_f32_16x16x32_bf16(Wk[0], bfrag, acc0, 0, 0, 0);
                acc1 = __builtin_amdgcn_mfma_f32_16x16x32_bf16(Wk[64], bfrag, acc1, 0, 0, 0);
                acc2 = __builtin_amdgcn_mfma_f32_16x16x32_bf16(Wk[128], bfrag, acc2, 0, 0, 0);
                acc3 = __builtin_amdgcn_mfma_f32_16x16x32_bf16(Wk[192], bfrag, acc3, 0, 0, 0);
            }
        }

        // epilogue: bias + relu in fp32; pooled contribution; h1 -> LDS (bf16, transposed)
        const float* biasP = l ? sBiasB : sBiasA;
        const float* wfcP = sWfcS + l * 64;
#pragma unroll
        for (int ot = 0; ot < 4; ++ot) {
            f32x4 a = (ot == 0) ? acc0 : (ot == 1) ? acc1 : (ot == 2) ? acc2 : acc3;
#pragma unroll
            for (int rreg = 0; rreg < 4; ++rreg) {
                int o = ot * 16 + q * 4 + rreg; // C/D: row = quad*4 + reg, col = lane&15
                float v = a[rreg] + biasP[o];
                v = fmaxf(v, 0.0f);
                contrib += v * wfcP[o];
                if (l == 0) sHT[d * 72 + o] = f2bf(v);
            }
        }
        // visibility of sHT writes to all waves is guaranteed by the next
        // chunk-loop's leading __syncthreads (l==1, chunk==0).
    }

    // ---- reduce contrib over 256 threads -> out[b] ----
#pragma unroll
    for (int off = 32; off > 0; off >>= 1)
        contrib += __shfl_down(contrib, off, 64);
    if (lane == 0) sRed[w] = contrib;
    __syncthreads();
    if (tid == 0) out[bb] = sRed[0] + sRed[1] + sRed[2] + sRed[3] + bfc[0];
}

extern "C" void kernel_launch(void* const* d_in, const int* in_sizes, int n_in,
                              void* d_out, int out_size, void* d_ws, size_t ws_size,
                              hipStream_t stream) {
    const float* x = (const float*)d_in[0];
    const float* W1 = (const float*)d_in[1];
    const float* b1 = (const float*)d_in[2];
    const float* W2 = (const float*)d_in[3];
    const float* b2 = (const float*)d_in[4];
    const float* Wfc = (const float*)d_in[5];
    const float* bfc = (const float*)d_in[6];
    float* out = (float*)d_out;

    unsigned short* Wf = (unsigned short*)d_ws; // 2 * 262144 bf16 = 1 MB

    prepack_kernel<<<2048, 256, 0, stream>>>(W1, W2, Wf);
    cin_kernel<<<1024, 256, 0, stream>>>(x, Wf, b1, b2, Wfc, bfc, out);
}

// Round 2
// 169.564 us; speedup vs baseline: 1.5268x; 1.5268x over previous
//
#include <hip/hip_runtime.h>

typedef short short8 __attribute__((ext_vector_type(8)));
typedef float f32x16 __attribute__((ext_vector_type(16)));
typedef unsigned int u32x4 __attribute__((ext_vector_type(4)));

#define CHUNK_ELEMS 8192   // 8 ksteps * 1024 bf16 = 16 KB
#define HT_STRIDE 72

__device__ __forceinline__ unsigned short f2bf(float f) {
    unsigned int u = __float_as_uint(f);
    u += 0x7fffu + ((u >> 16) & 1u);
    return (unsigned short)(u >> 16);
}
__device__ __forceinline__ float bf2f(unsigned short h) {
    return __uint_as_float(((unsigned int)h) << 16);
}

#ifdef __has_builtin
#if __has_builtin(__builtin_amdgcn_cvt_pk_bf16_f32)
#define HAVE_CVT_PK_BF16 1
#endif
#endif

// pack two f32 -> bf16x2 (RNE)
__device__ __forceinline__ unsigned int pk2bf(float lo, float hi) {
#ifdef HAVE_CVT_PK_BF16
    auto r = __builtin_amdgcn_cvt_pk_bf16_f32(lo, hi);
    return __builtin_bit_cast(unsigned int, r);
#else
    unsigned int a = __float_as_uint(lo);
    a += 0x7fffu + ((a >> 16) & 1u);
    unsigned int b = __float_as_uint(hi);
    b += 0x7fffu + ((b >> 16) & 1u);
    return (a >> 16) | (b & 0xffff0000u);
#endif
}

// Repack W (fp32 [o][c], c=i*64+j) into bf16 A-fragment order for 32x32x16:
// Wf[l][ks(256)][ot(2)][lane(64)][t(8)] = bf16(W_l[ot*32+(lane&31)][ks*16+(lane>>5)*8+t])
// Reads fully coalesced (wave = 512 consecutive floats of one o-row).
__global__ __launch_bounds__(256) void prepack_kernel(const float* __restrict__ W1,
                                                      const float* __restrict__ W2,
                                                      unsigned short* __restrict__ Wf) {
    int tid = blockIdx.x * 256 + threadIdx.x; // 0..65535
    int cg = tid & 511;        // c = cg*8
    int o = (tid >> 9) & 63;
    int l = tid >> 15;
    const float* W = l ? W2 : W1;
    const float4* src = (const float4*)(W + o * 4096 + cg * 8);
    float4 v0 = src[0];
    float4 v1 = src[1];
    int ks = cg >> 1;
    int q2 = cg & 1;
    int lane = (q2 << 5) | (o & 31);
    int ot = o >> 5;
    u32x4 pv;
    pv[0] = pk2bf(v0.x, v0.y);
    pv[1] = pk2bf(v0.z, v0.w);
    pv[2] = pk2bf(v1.x, v1.y);
    pv[3] = pk2bf(v1.z, v1.w);
    ((u32x4*)Wf)[((l * 256 + ks) * 2 + ot) * 64 + lane] = pv;
}

// async stage of one 16 KB W-chunk: wave-cooperative, 4 x global_load_lds(16B)/wave
__device__ __forceinline__ void stage_chunk(const unsigned short* g, unsigned short* s,
                                            int w, int lane) {
#pragma unroll
    for (int r = 0; r < 4; ++r) {
        const unsigned short* gp = g + w * 2048 + r * 512 + lane * 8;
        unsigned short* lp = s + w * 2048 + r * 512;
        __builtin_amdgcn_global_load_lds(
            (const __attribute__((address_space(1))) unsigned int*)gp,
            (__attribute__((address_space(3))) unsigned int*)lp,
            16, 0, 0);
    }
}

// Block = 2 batch elems, 4 waves: wave w -> (b_loc = w>>1, dt = w&1).
// Wave: d-tile of 32 (n31), all 64 o (2 otiles), full K. h/x factors live in
// registers; LDS carries only W fragments (double-buffered) + layer handoff.
__global__ __launch_bounds__(256, 3) void cin_kernel(const float* __restrict__ x,
                                                     const unsigned short* __restrict__ Wf,
                                                     const float* __restrict__ b1,
                                                     const float* __restrict__ b2,
                                                     const float* __restrict__ Wfc,
                                                     const float* __restrict__ bfc,
                                                     float* __restrict__ out) {
    __shared__ __align__(16) unsigned short sW[2 * CHUNK_ELEMS];          // 32 KB dbuf
    __shared__ __align__(16) unsigned short sHT[2][64 * HT_STRIDE];       // 18.4 KB handoff
    __shared__ float sBias[128], sWfcS[128], sRed[4];

    const int tid = threadIdx.x;
    const int w = tid >> 6;
    const int lane = tid & 63;
    const int q2 = lane >> 5;
    const int n31 = lane & 31;
    const int b_loc = w >> 1;
    const int dt = w & 1;
    const int d = dt * 32 + n31;
    const int bb = blockIdx.x;
    const float* xb = x + (bb * 2 + b_loc) * 4096;

    if (tid < 64) {
        sBias[tid] = b1[tid];
        sBias[64 + tid] = b2[tid];
        sWfcS[tid] = Wfc[tid];
        sWfcS[64 + tid] = Wfc[64 + tid];
    }

    stage_chunk(Wf, sW, w, lane); // chunk 0 -> buf 0 (async)

    // j-factor registers: lane needs h[jg*16 + q2*8 + t][d] only (layer 0: h = x, fp32)
    float hreg[4][8];
#pragma unroll
    for (int jg = 0; jg < 4; ++jg)
#pragma unroll
        for (int t = 0; t < 8; ++t)
            hreg[jg][t] = xb[(jg * 16 + q2 * 8 + t) * 64 + d];

    f32x16 acc0, acc1;
#pragma unroll
    for (int i = 0; i < 16; ++i) { acc0[i] = 0.0f; acc1[i] = 0.0f; }

    float contrib = 0.0f;
    float xvA = xb[d];        // i-row 0
    float xvB = xb[64 + d];   // i-row 1

    auto epilogue = [&](int l) {
#pragma unroll
        for (int ot = 0; ot < 2; ++ot) {
            const f32x16 a = ot ? acc1 : acc0;
#pragma unroll
            for (int r = 0; r < 16; ++r) {
                // C/D: col = lane&31 (=d), row = (r&3) + 8*(r>>2) + 4*q2
                int o = ot * 32 + (r & 3) + 8 * (r >> 2) + 4 * q2;
                float v = a[r] + sBias[l * 64 + o];
                v = fmaxf(v, 0.0f);
                contrib += v * sWfcS[l * 64 + o];
                if (l == 0) sHT[b_loc][d * HT_STRIDE + o] = f2bf(v);
            }
        }
        if (l == 0) {
            // wave-local handoff: reload j-factor regs from own rows
#pragma unroll
            for (int jg = 0; jg < 4; ++jg) {
                const unsigned short* hp = &sHT[b_loc][d * HT_STRIDE + jg * 16 + q2 * 8];
#pragma unroll
                for (int t = 0; t < 8; ++t) hreg[jg][t] = bf2f(hp[t]);
            }
#pragma unroll
            for (int i = 0; i < 16; ++i) { acc0[i] = 0.0f; acc1[i] = 0.0f; }
        }
    };

    for (int c = 0; c < 64; ++c) {
        __syncthreads(); // drains stage(c) vmcnt; orders compute(c-1) vs stage(c+1)
        if (c < 63) stage_chunk(Wf + (c + 1) * CHUNK_ELEMS,
                                sW + ((c + 1) & 1) * CHUNK_ELEMS, w, lane);
        if (c == 32) epilogue(0); // layer boundary (wave-local, no extra barrier)

        float xv0 = xvA, xv1 = xvB;
        if (c < 63) { // prefetch next chunk's i-rows (always from x)
            int i0n = ((c + 1) & 31) * 2;
            xvA = xb[i0n * 64 + d];
            xvB = xb[i0n * 64 + 64 + d];
        }
        const unsigned short* sWc = sW + (c & 1) * CHUNK_ELEMS;
#pragma unroll
        for (int k8 = 0; k8 < 8; ++k8) {
            const int jg = k8 & 3;              // j0 = jg*16, lane adds q2*8+t
            const float xv = (k8 < 4) ? xv0 : xv1;
            u32x4 pv;
            pv[0] = pk2bf(xv * hreg[jg][0], xv * hreg[jg][1]);
            pv[1] = pk2bf(xv * hreg[jg][2], xv * hreg[jg][3]);
            pv[2] = pk2bf(xv * hreg[jg][4], xv * hreg[jg][5]);
            pv[3] = pk2bf(xv * hreg[jg][6], xv * hreg[jg][7]);
            short8 bfrag = __builtin_bit_cast(short8, pv);
            const short8* Wk = (const short8*)(sWc + k8 * 1024);
            short8 a0 = Wk[lane];
            short8 a1 = Wk[64 + lane];
            acc0 = __builtin_amdgcn_mfma_f32_32x32x16_bf16(a0, bfrag, acc0, 0, 0, 0);
            acc1 = __builtin_amdgcn_mfma_f32_32x32x16_bf16(a1, bfrag, acc1, 0, 0, 0);
        }
    }
    epilogue(1);

    // reduce contrib: wave shuffle -> per-wave partial -> out
#pragma unroll
    for (int off = 32; off > 0; off >>= 1)
        contrib += __shfl_down(contrib, off, 64);
    if (lane == 0) sRed[w] = contrib;
    __syncthreads();
    if (tid == 0) {
        float fb = bfc[0];
        out[bb * 2 + 0] = sRed[0] + sRed[1] + fb;
        out[bb * 2 + 1] = sRed[2] + sRed[3] + fb;
    }
}

extern "C" void kernel_launch(void* const* d_in, const int* in_sizes, int n_in,
                              void* d_out, int out_size, void* d_ws, size_t ws_size,
                              hipStream_t stream) {
    const float* x = (const float*)d_in[0];
    const float* W1 = (const float*)d_in[1];
    const float* b1 = (const float*)d_in[2];
    const float* W2 = (const float*)d_in[3];
    const float* b2 = (const float*)d_in[4];
    const float* Wfc = (const float*)d_in[5];
    const float* bfc = (const float*)d_in[6];
    float* out = (float*)d_out;

    unsigned short* Wf = (unsigned short*)d_ws; // 2 * 262144 bf16 = 1 MB

    prepack_kernel<<<256, 256, 0, stream>>>(W1, W2, Wf);
    cin_kernel<<<512, 256, 0, stream>>>(x, Wf, b1, b2, Wfc, bfc, out);
}